// Round 1
// baseline (666.781 us; speedup 1.0000x reference)
//
#include <hip/hip_runtime.h>
#include <hip/hip_bf16.h>
#include <math.h>

#define T_TOK 2048
#define DM    1024
#define DF    4096
#define NE    8
#define BM    128
#define BN    128
#define BK    32
#define LDA   40   // LDS row stride in bf16 elements (40*2B=80B, multiple of 16B, breaks pow2 bank pattern)

typedef __attribute__((ext_vector_type(8))) short          bf16x8;
typedef __attribute__((ext_vector_type(8))) unsigned short ushort8;
typedef __attribute__((ext_vector_type(4))) float          f32x4;

__device__ __forceinline__ unsigned short f2bf(float f) {
  unsigned u = __builtin_bit_cast(unsigned, f);
  unsigned r = u + 0x7fffu + ((u >> 16) & 1u);   // RNE
  return (unsigned short)(r >> 16);
}

// ---------------- x f32 -> bf16 ----------------
__global__ void convert_x_kernel(const float* __restrict__ x, unsigned short* __restrict__ xb) {
  int i = blockIdx.x * blockDim.x + threadIdx.x;   // one thread per 8 elements
  const float* src = x + (size_t)i * 8;
  float4 a = *(const float4*)(src);
  float4 b = *(const float4*)(src + 4);
  ushort8 v;
  v[0] = f2bf(a.x); v[1] = f2bf(a.y); v[2] = f2bf(a.z); v[3] = f2bf(a.w);
  v[4] = f2bf(b.x); v[5] = f2bf(b.y); v[6] = f2bf(b.z); v[7] = f2bf(b.w);
  *(ushort8*)(xb + (size_t)i * 8) = v;
}

// ---------------- gating: one wave per token ----------------
__global__ __launch_bounds__(256) void gating_kernel(
    const float* __restrict__ x, const float* __restrict__ wg, const float* __restrict__ bg,
    int* __restrict__ cnt, int* __restrict__ perm, float* __restrict__ pw)
{
  int wid  = (blockIdx.x * blockDim.x + threadIdx.x) >> 6;   // token
  int lane = threadIdx.x & 63;
  if (wid >= T_TOK) return;
  const float* xr = x + (size_t)wid * DM;

  float acc[NE];
#pragma unroll
  for (int e = 0; e < NE; e++) acc[e] = 0.f;

  for (int d = lane; d < DM; d += 64) {
    float xv = xr[d];
    const float* wr = wg + (size_t)d * NE;
#pragma unroll
    for (int e = 0; e < NE; e++) acc[e] += xv * wr[e];
  }
#pragma unroll
  for (int off = 32; off > 0; off >>= 1) {
#pragma unroll
    for (int e = 0; e < NE; e++) acc[e] += __shfl_xor(acc[e], off, 64);
  }
  if (lane == 0) {
    float v[NE];
#pragma unroll
    for (int e = 0; e < NE; e++) v[e] = acc[e] + bg[e];
    // top-2, strict > keeps lowest index on ties (matches lax.top_k)
    int i0 = 0; float v0 = v[0];
#pragma unroll
    for (int e = 1; e < NE; e++) { if (v[e] > v0) { v0 = v[e]; i0 = e; } }
    int i1 = -1; float v1 = -INFINITY;
#pragma unroll
    for (int e = 0; e < NE; e++) { if (e != i0 && v[e] > v1) { v1 = v[e]; i1 = e; } }
    float e1 = expf(v1 - v0);
    float s  = 1.f + e1;
    float w0 = 1.f / s, w1 = e1 / s;
    int p0 = atomicAdd(&cnt[i0], 1);
    perm[i0 * T_TOK + p0] = wid; pw[i0 * T_TOK + p0] = w0;
    int p1 = atomicAdd(&cnt[i1], 1);
    perm[i1 * T_TOK + p1] = wid; pw[i1 * T_TOK + p1] = w1;
  }
}

// ---------------- pad lists to BM multiple + exclusive scan ----------------
__global__ void pad_scan_kernel(const int* __restrict__ cnt, int* __restrict__ cntpad,
                                int* __restrict__ offs, int* __restrict__ perm, float* __restrict__ pw)
{
  if (threadIdx.x == 0) {
    int o = 0;
    for (int e = 0; e < NE; e++) {
      int c  = cnt[e];
      int cp = (c + BM - 1) / BM * BM;
      cntpad[e] = cp;
      offs[e]   = o;
      o += cp;
    }
    offs[NE] = o;
  }
  // pad entries (cnt is read-only here, no sync needed: recompute cp per thread)
  for (int e = 0; e < NE; e++) {
    int c  = cnt[e];
    int cp = (c + BM - 1) / BM * BM;
    for (int i = c + threadIdx.x; i < cp; i += blockDim.x) {
      perm[e * T_TOK + i] = 0;
      pw[e * T_TOK + i]   = 0.f;
    }
  }
}

// ---------------- expert GEMM (MFMA bf16), 128x128 tile, 4 waves ----------------
// PHASE 1: H = relu(X_e * W1_e + b1)   (A rows gathered via perm from xb)
// PHASE 2: out[token] += w * (H_e * W2_e + b2)   (K-split, atomic combine)
template<int PHASE, int KTOT, int NCOLS, int KSPLIT>
__global__ __launch_bounds__(256) void moe_gemm(
    const unsigned short* __restrict__ Asrc,   // xb (phase1) or H (phase2)
    const float* __restrict__ Wbase,           // w1 or w2 (with expert dim)
    const float* __restrict__ bias,            // b1 or b2 (with expert dim)
    const int* __restrict__ cntpad, const int* __restrict__ offs,
    const int* __restrict__ perm, const float* __restrict__ pw,
    unsigned short* __restrict__ Hout,         // phase1 output
    float* __restrict__ out)                   // phase2 output
{
  const int e  = blockIdx.z;
  const int mt = blockIdx.y;
  const int nt = blockIdx.x / KSPLIT;
  const int ks = blockIdx.x % KSPLIT;
  const int cp = cntpad[e];
  if (mt * BM >= cp) return;
  const int tid = threadIdx.x;
  const int oe  = offs[e];

  __shared__ unsigned short As[BM * LDA];
  __shared__ unsigned short Bs[BN * LDA];

  // A staging: thread covers row am, 16 consecutive k (two 16B chunks)
  const int am = tid >> 1;
  const int ak = (tid & 1) * 16;
  size_t arow_off;
  if (PHASE == 1) {
    int token = perm[e * T_TOK + mt * BM + am];
    arow_off = (size_t)token * DM;
  } else {
    arow_off = (size_t)(oe + mt * BM + am) * (size_t)KTOT;
  }

  // B staging: thread covers col bn, two k-groups of 8 (strided dword loads, f32->bf16, transposed store)
  const int bn  = tid & 127;
  const int bk0 = (tid >> 7) * 16;
  const float* Wexp = Wbase + (size_t)e * KTOT * NCOLS + (size_t)nt * BN;

  const int kbase0 = ks * (KTOT / KSPLIT);
  const int KITERS = (KTOT / KSPLIT) / BK;

  const int wid  = tid >> 6;
  const int lane = tid & 63;
  const int wm   = (wid & 1) * 64;
  const int wn   = (wid >> 1) * 64;
  const int lrow = lane & 15;
  const int lk   = (lane >> 4) * 8;

  f32x4 acc[4][4];
#pragma unroll
  for (int i = 0; i < 4; i++)
#pragma unroll
    for (int j = 0; j < 4; j++) acc[i][j] = (f32x4){0.f, 0.f, 0.f, 0.f};

  for (int kt = 0; kt < KITERS; kt++) {
    const int kb = kbase0 + kt * BK;
    {  // A: 32B/thread, already bf16
      const unsigned short* src = Asrc + arow_off + kb + ak;
      uint4 v0 = *(const uint4*)(src);
      uint4 v1 = *(const uint4*)(src + 8);
      *(uint4*)&As[am * LDA + ak]     = v0;
      *(uint4*)&As[am * LDA + ak + 8] = v1;
    }
    {  // B: 2 tasks x (8 strided f32 loads -> bf16x8 -> one 16B LDS write, transposed)
#pragma unroll
      for (int t2 = 0; t2 < 2; t2++) {
        const int kk = bk0 + t2 * 8;
        const float* wp = Wexp + (size_t)(kb + kk) * NCOLS + bn;
        ushort8 tv;
#pragma unroll
        for (int j = 0; j < 8; j++) tv[j] = f2bf(wp[(size_t)j * NCOLS]);
        *(ushort8*)&Bs[bn * LDA + kk] = tv;
      }
    }
    __syncthreads();
    bf16x8 af[4], bfr[4];
#pragma unroll
    for (int i = 0; i < 4; i++) af[i]  = *(const bf16x8*)&As[(wm + i * 16 + lrow) * LDA + lk];
#pragma unroll
    for (int j = 0; j < 4; j++) bfr[j] = *(const bf16x8*)&Bs[(wn + j * 16 + lrow) * LDA + lk];
#pragma unroll
    for (int i = 0; i < 4; i++)
#pragma unroll
      for (int j = 0; j < 4; j++)
        acc[i][j] = __builtin_amdgcn_mfma_f32_16x16x32_bf16(af[i], bfr[j], acc[i][j], 0, 0, 0);
    __syncthreads();
  }

  // epilogue: C/D layout col=lane&15, row=(lane>>4)*4+reg
  const int crow = (lane >> 4) * 4;
  const int ccol = lane & 15;
#pragma unroll
  for (int j = 0; j < 4; j++) {
    const int gn = nt * BN + wn + j * 16 + ccol;
    const float bv = bias[e * NCOLS + gn];
#pragma unroll
    for (int i = 0; i < 4; i++) {
#pragma unroll
      for (int r = 0; r < 4; r++) {
        const int lm = wm + i * 16 + crow + r;
        float v = acc[i][j][r];
        if (PHASE == 1) {
          v += bv;
          v = v > 0.f ? v : 0.f;
          Hout[(size_t)(oe + mt * BM + lm) * NCOLS + gn] = f2bf(v);
        } else {
          if (ks == 0) v += bv;
          const int li    = e * T_TOK + mt * BM + lm;
          const int token = perm[li];
          const float w   = pw[li];
          atomicAdd(&out[(size_t)token * NCOLS + gn], w * v);
        }
      }
    }
  }
}

extern "C" void kernel_launch(void* const* d_in, const int* in_sizes, int n_in,
                              void* d_out, int out_size, void* d_ws, size_t ws_size,
                              hipStream_t stream) {
  const float* x  = (const float*)d_in[0];
  const float* wg = (const float*)d_in[1];
  const float* bg = (const float*)d_in[2];
  const float* w1 = (const float*)d_in[3];
  const float* b1 = (const float*)d_in[4];
  const float* w2 = (const float*)d_in[5];
  const float* b2 = (const float*)d_in[6];
  float* out = (float*)d_out;

  // ---- workspace layout ----
  const size_t XB_BYTES   = (size_t)T_TOK * DM * 2;        // 4 MB bf16 x
  const size_t PERM_BYTES = (size_t)NE * T_TOK * 4;        // 64 KB
  const size_t PW_BYTES   = (size_t)NE * T_TOK * 4;        // 64 KB
  char* wsp = (char*)d_ws;
  unsigned short* xb  = (unsigned short*)wsp;
  int*   cnt    = (int*)(wsp + XB_BYTES);                  // 8 ints
  int*   cntpad = cnt + 8;                                 // 8 ints
  int*   offs   = cnt + 16;                                // 9 ints
  int*   perm   = (int*)(wsp + XB_BYTES + 256);
  float* pwt    = (float*)(wsp + XB_BYTES + 256 + PERM_BYTES);
  unsigned short* H = (unsigned short*)(wsp + XB_BYTES + 256 + PERM_BYTES + PW_BYTES);
  // H capacity: (2*T_TOK + NE*BM) rows x DF bf16 = 5120*4096*2 = 40 MB

  hipMemsetAsync(cnt, 0, 256, stream);
  hipMemsetAsync(d_out, 0, (size_t)T_TOK * DM * 4, stream);

  convert_x_kernel<<<(T_TOK * DM / 8) / 256, 256, 0, stream>>>(x, xb);
  gating_kernel<<<T_TOK / 4, 256, 0, stream>>>(x, wg, bg, cnt, perm, pwt);
  pad_scan_kernel<<<1, 256, 0, stream>>>(cnt, cntpad, offs, perm, pwt);

  moe_gemm<1, DM, DF, 1><<<dim3(DF / BN, T_TOK / BM, NE), 256, 0, stream>>>(
      xb, w1, b1, cntpad, offs, perm, pwt, H, nullptr);
  moe_gemm<2, DF, DM, 4><<<dim3((DM / BN) * 4, T_TOK / BM, NE), 256, 0, stream>>>(
      H, w2, b2, cntpad, offs, perm, pwt, nullptr, out);
}

// Round 2
// 639.777 us; speedup vs baseline: 1.0422x; 1.0422x over previous
//
#include <hip/hip_runtime.h>
#include <hip/hip_bf16.h>
#include <math.h>

#define T_TOK 2048
#define DM    1024
#define DF    4096
#define NE    8
#define BM    128
#define BN    128
#define BK    32
#define LDA   40   // LDS row stride in bf16 elements (80B: 16B-aligned for b128, breaks pow2 bank pattern)

typedef __attribute__((ext_vector_type(8))) short          bf16x8;
typedef __attribute__((ext_vector_type(8))) unsigned short ushort8;
typedef __attribute__((ext_vector_type(4))) float          f32x4;

__device__ __forceinline__ unsigned short f2bf(float f) {
  unsigned u = __builtin_bit_cast(unsigned, f);
  unsigned r = u + 0x7fffu + ((u >> 16) & 1u);   // RNE
  return (unsigned short)(r >> 16);
}

// ---------------- x f32 -> bf16 ----------------
__global__ void convert_x_kernel(const float* __restrict__ x, unsigned short* __restrict__ xb) {
  int i = blockIdx.x * blockDim.x + threadIdx.x;   // one thread per 8 elements
  const float* src = x + (size_t)i * 8;
  float4 a = *(const float4*)(src);
  float4 b = *(const float4*)(src + 4);
  ushort8 v;
  v[0] = f2bf(a.x); v[1] = f2bf(a.y); v[2] = f2bf(a.z); v[3] = f2bf(a.w);
  v[4] = f2bf(b.x); v[5] = f2bf(b.y); v[6] = f2bf(b.z); v[7] = f2bf(b.w);
  *(ushort8*)(xb + (size_t)i * 8) = v;
}

// ---------------- weight convert + transpose: W[E][K][N] f32 -> Wt[E][N][K] bf16 ----------------
// grid: (N/128, K/32, E), 256 threads. LDS f32 tile with +1 pad; coalesced both sides.
template<int K, int N>
__global__ __launch_bounds__(256) void transpose_convert(
    const float* __restrict__ W, unsigned short* __restrict__ Wt)
{
  const int e  = blockIdx.z;
  const int k0 = blockIdx.y * 32;
  const int n0 = blockIdx.x * 128;
  const float* Wp = W + (size_t)e * K * N;
  unsigned short* Wo = Wt + (size_t)e * N * K;
  __shared__ float Ls[32][129];
  const int tid = threadIdx.x;
  {  // load 32k x 128n tile, float4-coalesced
    const int kl = tid >> 5;          // 0..7
    const int nl = (tid & 31) * 4;
#pragma unroll
    for (int p = 0; p < 4; p++) {
      const int k = kl + p * 8;
      float4 v = *(const float4*)(Wp + (size_t)(k0 + k) * N + n0 + nl);
      Ls[k][nl + 0] = v.x; Ls[k][nl + 1] = v.y; Ls[k][nl + 2] = v.z; Ls[k][nl + 3] = v.w;
    }
  }
  __syncthreads();
  {  // store transposed: thread = (n, k-chunk of 8); conflict-free column reads (129 stride)
    const int n  = tid & 127;
    const int c0 = tid >> 7;          // 0..1
#pragma unroll
    for (int p = 0; p < 2; p++) {
      const int c = c0 + p * 2;       // 0..3
      ushort8 o;
#pragma unroll
      for (int j = 0; j < 8; j++) o[j] = f2bf(Ls[c * 8 + j][n]);
      *(ushort8*)(Wo + (size_t)(n0 + n) * K + k0 + c * 8) = o;
    }
  }
}

// ---------------- gating: one wave per token ----------------
__global__ __launch_bounds__(256) void gating_kernel(
    const float* __restrict__ x, const float* __restrict__ wg, const float* __restrict__ bg,
    int* __restrict__ cnt, int* __restrict__ perm, float* __restrict__ pw)
{
  int wid  = (blockIdx.x * blockDim.x + threadIdx.x) >> 6;   // token
  int lane = threadIdx.x & 63;
  if (wid >= T_TOK) return;
  const float* xr = x + (size_t)wid * DM;

  float acc[NE];
#pragma unroll
  for (int e = 0; e < NE; e++) acc[e] = 0.f;

  for (int d = lane; d < DM; d += 64) {
    float xv = xr[d];
    const float* wr = wg + (size_t)d * NE;
#pragma unroll
    for (int e = 0; e < NE; e++) acc[e] += xv * wr[e];
  }
#pragma unroll
  for (int off = 32; off > 0; off >>= 1) {
#pragma unroll
    for (int e = 0; e < NE; e++) acc[e] += __shfl_xor(acc[e], off, 64);
  }
  if (lane == 0) {
    float v[NE];
#pragma unroll
    for (int e = 0; e < NE; e++) v[e] = acc[e] + bg[e];
    int i0 = 0; float v0 = v[0];
#pragma unroll
    for (int e = 1; e < NE; e++) { if (v[e] > v0) { v0 = v[e]; i0 = e; } }
    int i1 = -1; float v1 = -INFINITY;
#pragma unroll
    for (int e = 0; e < NE; e++) { if (e != i0 && v[e] > v1) { v1 = v[e]; i1 = e; } }
    float e1 = expf(v1 - v0);
    float s  = 1.f + e1;
    float w0 = 1.f / s, w1 = e1 / s;
    int p0 = atomicAdd(&cnt[i0], 1);
    perm[i0 * T_TOK + p0] = wid; pw[i0 * T_TOK + p0] = w0;
    int p1 = atomicAdd(&cnt[i1], 1);
    perm[i1 * T_TOK + p1] = wid; pw[i1 * T_TOK + p1] = w1;
  }
}

// ---------------- pad lists to BM multiple + exclusive scan ----------------
__global__ void pad_scan_kernel(const int* __restrict__ cnt, int* __restrict__ cntpad,
                                int* __restrict__ offs, int* __restrict__ perm, float* __restrict__ pw)
{
  if (threadIdx.x == 0) {
    int o = 0;
    for (int e = 0; e < NE; e++) {
      int c  = cnt[e];
      int cp = (c + BM - 1) / BM * BM;
      cntpad[e] = cp;
      offs[e]   = o;
      o += cp;
    }
    offs[NE] = o;
  }
  for (int e = 0; e < NE; e++) {
    int c  = cnt[e];
    int cp = (c + BM - 1) / BM * BM;
    for (int i = c + threadIdx.x; i < cp; i += blockDim.x) {
      perm[e * T_TOK + i] = 0;
      pw[e * T_TOK + i]   = 0.f;
    }
  }
}

// ======== v2 GEMM: bf16 A and pre-transposed bf16 B, register-prefetch pipeline ========
// PHASE 1: H = relu(X_e * W1 + b1)   PHASE 2: out[token] += w * (H_e * W2 + b2)
template<int PHASE, int KTOT, int NCOLS, int KSPLIT>
__global__ __launch_bounds__(256, 2) void moe_gemm2(
    const unsigned short* __restrict__ Asrc,
    const unsigned short* __restrict__ Bt,     // [E][NCOLS][KTOT] bf16 (transposed)
    const float* __restrict__ bias,
    const int* __restrict__ cntpad, const int* __restrict__ offs,
    const int* __restrict__ perm, const float* __restrict__ pw,
    unsigned short* __restrict__ Hout, float* __restrict__ out)
{
  const int e  = blockIdx.z;
  const int mt = blockIdx.y;
  const int nt = blockIdx.x / KSPLIT;
  const int ks = blockIdx.x % KSPLIT;
  const int cp = cntpad[e];
  if (mt * BM >= cp) return;
  const int tid = threadIdx.x;
  const int oe  = offs[e];

  __shared__ unsigned short As[BM * LDA];
  __shared__ unsigned short Bs[BN * LDA];

  // staging: thread covers row am (0..127), 16 consecutive k (two b128 chunks) for BOTH A and B
  const int am = tid >> 1;
  const int ak = (tid & 1) * 16;
  size_t arow;
  if (PHASE == 1) {
    int token = perm[e * T_TOK + mt * BM + am];
    arow = (size_t)token * KTOT;
  } else {
    arow = (size_t)(oe + mt * BM + am) * (size_t)KTOT;
  }
  const int kbase0 = ks * (KTOT / KSPLIT);
  const unsigned short* Ap = Asrc + arow + kbase0 + ak;
  const unsigned short* Bp = Bt + ((size_t)e * NCOLS + (size_t)nt * BN + am) * KTOT + kbase0 + ak;
  const int KITERS = (KTOT / KSPLIT) / BK;

  const int wid  = tid >> 6;
  const int lane = tid & 63;
  const int wm   = (wid & 1) * 64;
  const int wn   = (wid >> 1) * 64;
  const int lrow = lane & 15;
  const int lk   = (lane >> 4) * 8;

  f32x4 acc[4][4];
#pragma unroll
  for (int i = 0; i < 4; i++)
#pragma unroll
    for (int j = 0; j < 4; j++) acc[i][j] = (f32x4){0.f, 0.f, 0.f, 0.f};

  // prologue: stage tile 0
  uint4 ra0 = *(const uint4*)(Ap);
  uint4 ra1 = *(const uint4*)(Ap + 8);
  uint4 rb0 = *(const uint4*)(Bp);
  uint4 rb1 = *(const uint4*)(Bp + 8);
  *(uint4*)&As[am * LDA + ak]     = ra0;
  *(uint4*)&As[am * LDA + ak + 8] = ra1;
  *(uint4*)&Bs[am * LDA + ak]     = rb0;
  *(uint4*)&Bs[am * LDA + ak + 8] = rb1;

  for (int kt = 0; kt < KITERS; kt++) {
    __syncthreads();                          // LDS writes (tile kt) visible
    if (kt + 1 < KITERS) {                    // prefetch tile kt+1 into registers
      const int kb = (kt + 1) * BK;
      ra0 = *(const uint4*)(Ap + kb);
      ra1 = *(const uint4*)(Ap + kb + 8);
      rb0 = *(const uint4*)(Bp + kb);
      rb1 = *(const uint4*)(Bp + kb + 8);
    }
    bf16x8 af[4], bfr[4];
#pragma unroll
    for (int i = 0; i < 4; i++) af[i]  = *(const bf16x8*)&As[(wm + i * 16 + lrow) * LDA + lk];
#pragma unroll
    for (int j = 0; j < 4; j++) bfr[j] = *(const bf16x8*)&Bs[(wn + j * 16 + lrow) * LDA + lk];
#pragma unroll
    for (int i = 0; i < 4; i++)
#pragma unroll
      for (int j = 0; j < 4; j++)
        acc[i][j] = __builtin_amdgcn_mfma_f32_16x16x32_bf16(af[i], bfr[j], acc[i][j], 0, 0, 0);
    __syncthreads();                          // frags consumed; safe to overwrite LDS
    if (kt + 1 < KITERS) {
      *(uint4*)&As[am * LDA + ak]     = ra0;
      *(uint4*)&As[am * LDA + ak + 8] = ra1;
      *(uint4*)&Bs[am * LDA + ak]     = rb0;
      *(uint4*)&Bs[am * LDA + ak + 8] = rb1;
    }
  }

  // epilogue: C/D layout col=lane&15, row=(lane>>4)*4+reg
  const int crow = (lane >> 4) * 4;
  const int ccol = lane & 15;
#pragma unroll
  for (int j = 0; j < 4; j++) {
    const int gn = nt * BN + wn + j * 16 + ccol;
    const float bv = bias[e * NCOLS + gn];
#pragma unroll
    for (int i = 0; i < 4; i++) {
#pragma unroll
      for (int r = 0; r < 4; r++) {
        const int lm = wm + i * 16 + crow + r;
        float v = acc[i][j][r];
        if (PHASE == 1) {
          v += bv;
          v = v > 0.f ? v : 0.f;
          Hout[(size_t)(oe + mt * BM + lm) * NCOLS + gn] = f2bf(v);
        } else {
          if (ks == 0) v += bv;
          const int li    = e * T_TOK + mt * BM + lm;
          const int token = perm[li];
          const float w   = pw[li];
          atomicAdd(&out[(size_t)token * NCOLS + gn], w * v);
        }
      }
    }
  }
}

// ======== v1 GEMM (round-1 fallback, f32 weights in-flight) — used only if ws too small ========
template<int PHASE, int KTOT, int NCOLS, int KSPLIT>
__global__ __launch_bounds__(256) void moe_gemm_v1(
    const unsigned short* __restrict__ Asrc,
    const float* __restrict__ Wbase,
    const float* __restrict__ bias,
    const int* __restrict__ cntpad, const int* __restrict__ offs,
    const int* __restrict__ perm, const float* __restrict__ pw,
    unsigned short* __restrict__ Hout, float* __restrict__ out)
{
  const int e  = blockIdx.z;
  const int mt = blockIdx.y;
  const int nt = blockIdx.x / KSPLIT;
  const int ks = blockIdx.x % KSPLIT;
  const int cp = cntpad[e];
  if (mt * BM >= cp) return;
  const int tid = threadIdx.x;
  const int oe  = offs[e];

  __shared__ unsigned short As[BM * LDA];
  __shared__ unsigned short Bs[BN * LDA];

  const int am = tid >> 1;
  const int ak = (tid & 1) * 16;
  size_t arow_off;
  if (PHASE == 1) {
    int token = perm[e * T_TOK + mt * BM + am];
    arow_off = (size_t)token * KTOT;
  } else {
    arow_off = (size_t)(oe + mt * BM + am) * (size_t)KTOT;
  }
  const int bn  = tid & 127;
  const int bk0 = (tid >> 7) * 16;
  const float* Wexp = Wbase + (size_t)e * KTOT * NCOLS + (size_t)nt * BN;
  const int kbase0 = ks * (KTOT / KSPLIT);
  const int KITERS = (KTOT / KSPLIT) / BK;
  const int wid  = tid >> 6;
  const int lane = tid & 63;
  const int wm   = (wid & 1) * 64;
  const int wn   = (wid >> 1) * 64;
  const int lrow = lane & 15;
  const int lk   = (lane >> 4) * 8;

  f32x4 acc[4][4];
#pragma unroll
  for (int i = 0; i < 4; i++)
#pragma unroll
    for (int j = 0; j < 4; j++) acc[i][j] = (f32x4){0.f, 0.f, 0.f, 0.f};

  for (int kt = 0; kt < KITERS; kt++) {
    const int kb = kbase0 + kt * BK;
    {
      const unsigned short* src = Asrc + arow_off + kb + ak;
      uint4 v0 = *(const uint4*)(src);
      uint4 v1 = *(const uint4*)(src + 8);
      *(uint4*)&As[am * LDA + ak]     = v0;
      *(uint4*)&As[am * LDA + ak + 8] = v1;
    }
#pragma unroll
    for (int t2 = 0; t2 < 2; t2++) {
      const int kk = bk0 + t2 * 8;
      const float* wp = Wexp + (size_t)(kb + kk) * NCOLS + bn;
      ushort8 tv;
#pragma unroll
      for (int j = 0; j < 8; j++) tv[j] = f2bf(wp[(size_t)j * NCOLS]);
      *(ushort8*)&Bs[bn * LDA + kk] = tv;
    }
    __syncthreads();
    bf16x8 af[4], bfr[4];
#pragma unroll
    for (int i = 0; i < 4; i++) af[i]  = *(const bf16x8*)&As[(wm + i * 16 + lrow) * LDA + lk];
#pragma unroll
    for (int j = 0; j < 4; j++) bfr[j] = *(const bf16x8*)&Bs[(wn + j * 16 + lrow) * LDA + lk];
#pragma unroll
    for (int i = 0; i < 4; i++)
#pragma unroll
      for (int j = 0; j < 4; j++)
        acc[i][j] = __builtin_amdgcn_mfma_f32_16x16x32_bf16(af[i], bfr[j], acc[i][j], 0, 0, 0);
    __syncthreads();
  }

  const int crow = (lane >> 4) * 4;
  const int ccol = lane & 15;
#pragma unroll
  for (int j = 0; j < 4; j++) {
    const int gn = nt * BN + wn + j * 16 + ccol;
    const float bv = bias[e * NCOLS + gn];
#pragma unroll
    for (int i = 0; i < 4; i++) {
#pragma unroll
      for (int r = 0; r < 4; r++) {
        const int lm = wm + i * 16 + crow + r;
        float v = acc[i][j][r];
        if (PHASE == 1) {
          v += bv;
          v = v > 0.f ? v : 0.f;
          Hout[(size_t)(oe + mt * BM + lm) * NCOLS + gn] = f2bf(v);
        } else {
          if (ks == 0) v += bv;
          const int li    = e * T_TOK + mt * BM + lm;
          const int token = perm[li];
          const float w   = pw[li];
          atomicAdd(&out[(size_t)token * NCOLS + gn], w * v);
        }
      }
    }
  }
}

extern "C" void kernel_launch(void* const* d_in, const int* in_sizes, int n_in,
                              void* d_out, int out_size, void* d_ws, size_t ws_size,
                              hipStream_t stream) {
  const float* x  = (const float*)d_in[0];
  const float* wg = (const float*)d_in[1];
  const float* bg = (const float*)d_in[2];
  const float* w1 = (const float*)d_in[3];
  const float* b1 = (const float*)d_in[4];
  const float* w2 = (const float*)d_in[5];
  const float* b2 = (const float*)d_in[6];
  float* out = (float*)d_out;

  // ---- workspace layout ----
  const size_t XB_BYTES   = (size_t)T_TOK * DM * 2;          // 4 MB
  const size_t PERM_BYTES = (size_t)NE * T_TOK * 4;          // 64 KB
  const size_t PW_BYTES   = (size_t)NE * T_TOK * 4;          // 64 KB
  const size_t H_BYTES    = (size_t)(2 * T_TOK + NE * BM) * DF * 2;  // 40 MB
  const size_t W1T_BYTES  = (size_t)NE * DF * DM * 2;        // 64 MB
  const size_t W2T_BYTES  = (size_t)NE * DM * DF * 2;        // 64 MB

  char* wsp = (char*)d_ws;
  size_t off = 0;
  unsigned short* xb = (unsigned short*)(wsp + off); off += XB_BYTES;
  int*   cnt    = (int*)(wsp + off); off += 256;             // cnt/cntpad/offs packed
  int*   cntpad = cnt + 8;
  int*   offs   = cnt + 16;
  int*   perm   = (int*)(wsp + off);   off += PERM_BYTES;
  float* pwt    = (float*)(wsp + off); off += PW_BYTES;
  unsigned short* H   = (unsigned short*)(wsp + off); off += H_BYTES;
  unsigned short* w1t = (unsigned short*)(wsp + off); off += W1T_BYTES;
  unsigned short* w2t = (unsigned short*)(wsp + off); off += W2T_BYTES;
  const size_t REQUIRED = off;

  hipMemsetAsync(cnt, 0, 256, stream);
  hipMemsetAsync(d_out, 0, (size_t)T_TOK * DM * 4, stream);

  convert_x_kernel<<<(T_TOK * DM / 8) / 256, 256, 0, stream>>>(x, xb);
  gating_kernel<<<T_TOK / 4, 256, 0, stream>>>(x, wg, bg, cnt, perm, pwt);
  pad_scan_kernel<<<1, 256, 0, stream>>>(cnt, cntpad, offs, perm, pwt);

  if (ws_size >= REQUIRED) {
    // convert + transpose weights to bf16 [E][N][K]
    transpose_convert<DM, DF><<<dim3(DF / 128, DM / 32, NE), 256, 0, stream>>>(w1, w1t);
    transpose_convert<DF, DM><<<dim3(DM / 128, DF / 32, NE), 256, 0, stream>>>(w2, w2t);

    moe_gemm2<1, DM, DF, 1><<<dim3(DF / BN, T_TOK / BM, NE), 256, 0, stream>>>(
        xb, w1t, b1, cntpad, offs, perm, pwt, H, nullptr);
    moe_gemm2<2, DF, DM, 2><<<dim3((DM / BN) * 2, T_TOK / BM, NE), 256, 0, stream>>>(
        H, w2t, b2, cntpad, offs, perm, pwt, nullptr, out);
  } else {
    // fallback: round-1 path (needs only ~46 MB of ws)
    moe_gemm_v1<1, DM, DF, 1><<<dim3(DF / BN, T_TOK / BM, NE), 256, 0, stream>>>(
        xb, w1, b1, cntpad, offs, perm, pwt, H, nullptr);
    moe_gemm_v1<2, DF, DM, 4><<<dim3((DM / BN) * 4, T_TOK / BM, NE), 256, 0, stream>>>(
        H, w2, b2, cntpad, offs, perm, pwt, nullptr, out);
  }
}